// Round 7
// baseline (930.050 us; speedup 1.0000x reference)
//
#include <hip/hip_runtime.h>

#define N_USERS 100000
#define N_ITEMS 50000
#define N_NODES (N_USERS + N_ITEMS)   // 150000
#define DIM 64
#define NNZ_TOTAL 10000000
#define TOTAL (N_NODES * DIM)         // 9,600,000 floats
#define TOTAL4 (TOTAL / 4)            // 2,400,000 float4
#define USZ4 (N_USERS * DIM / 4)      // 1,600,000 float4

#define BROWS 256                     // rows per bucket
#define NB ((N_NODES + BROWS - 1) / BROWS)   // 586
#define SCHUNK 16384                  // edges per scatter chunk
#define SGRD ((NNZ_TOTAL + SCHUNK - 1) / SCHUNK)  // 611
#define COLMASK 0x3FFFF               // 18 bits for col

__device__ __forceinline__ float bf2f(unsigned short u) {
    return __uint_as_float(((unsigned)u) << 16);
}
__device__ __forceinline__ unsigned short f2bf(float f) {
    unsigned b = __float_as_uint(f);
    b += 0x7FFFu + ((b >> 16) & 1u);   // RNE
    return (unsigned short)(b >> 16);
}

// ===========================================================================
// init: T0 = bf16(concat(user,item)); acc(d_out) = f32 concat
// ===========================================================================
__global__ __launch_bounds__(256) void k_init(const float4* __restrict__ user,
                                              const float4* __restrict__ item,
                                              ushort4* __restrict__ T0,
                                              float4* __restrict__ acc) {
    const int stride = gridDim.x * blockDim.x;
    for (int i = blockIdx.x * blockDim.x + threadIdx.x; i < TOTAL4; i += stride) {
        float4 v = (i < USZ4) ? user[i] : item[i - USZ4];
        acc[i] = v;
        ushort4 t;
        t.x = f2bf(v.x); t.y = f2bf(v.y); t.z = f2bf(v.z); t.w = f2bf(v.w);
        T0[i] = t;
    }
}

// ===========================================================================
// Bucketed CSR build. cnt matrix layout: cnt[b * SGRD + g]  (b-major)
// ===========================================================================
__global__ __launch_bounds__(256) void k_lhist(const int* __restrict__ row,
                                               int* __restrict__ cnt) {
    __shared__ int h[NB];
    for (int i = threadIdx.x; i < NB; i += 256) h[i] = 0;
    __syncthreads();
    const int g = blockIdx.x;
    const int lo = g * SCHUNK;
    const int hi = (lo + SCHUNK < NNZ_TOTAL) ? lo + SCHUNK : NNZ_TOTAL;
    for (int e = lo + threadIdx.x; e < hi; e += 256)
        atomicAdd(&h[row[e] >> 8], 1);
    __syncthreads();
    for (int b = threadIdx.x; b < NB; b += 256)
        cnt[b * SGRD + g] = h[b];
}

// scan phase 1: per-bucket row sums (586 blocks, coalesced)
__global__ __launch_bounds__(256) void k_rowsum(const int* __restrict__ cnt,
                                                int* __restrict__ rowsum) {
    __shared__ int lds[256];
    const int b = blockIdx.x;
    const int t = threadIdx.x;
    int s = 0;
    for (int k = t; k < SGRD; k += 256) s += cnt[b * SGRD + k];
    lds[t] = s;
    __syncthreads();
    #pragma unroll
    for (int off = 128; off > 0; off >>= 1) {
        if (t < off) lds[t] += lds[t + off];
        __syncthreads();
    }
    if (t == 0) rowsum[b] = lds[0];
}

// scan phase 2: exclusive scan of 586 row sums (single tiny block)
__global__ __launch_bounds__(1024) void k_sscan(const int* __restrict__ rowsum,
                                                int* __restrict__ bbase) {
    __shared__ int lds[1024];
    const int t = threadIdx.x;
    const int x = (t < NB) ? rowsum[t] : 0;
    lds[t] = x;
    __syncthreads();
    for (int off = 1; off < 1024; off <<= 1) {
        const int y = (t >= off) ? lds[t - off] : 0;
        __syncthreads();
        lds[t] += y;
        __syncthreads();
    }
    if (t < NB) bbase[t] = lds[t] - x;
    if (t == 1023) bbase[NB] = lds[1023];   // == NNZ
}

// scan phase 3: per-bucket exclusive scan over SGRD entries + base, in place
__global__ __launch_bounds__(1024) void k_rowscan(int* __restrict__ cnt,
                                                  const int* __restrict__ bbase) {
    __shared__ int lds[1024];
    const int b = blockIdx.x;
    const int t = threadIdx.x;
    const int x = (t < SGRD) ? cnt[b * SGRD + t] : 0;
    lds[t] = x;
    __syncthreads();
    for (int off = 1; off < 1024; off <<= 1) {
        const int y = (t >= off) ? lds[t - off] : 0;
        __syncthreads();
        lds[t] += y;
        __syncthreads();
    }
    if (t < SGRD) cnt[b * SGRD + t] = bbase[b] + lds[t] - x;   // exclusive + base
}

// LDS-staged scatter: chunk-sort edge ids by bucket, then write bucket runs
// contiguously -> coalesced global writes, ~1.2x amp instead of 3.5x.
__global__ __launch_bounds__(1024) void k_lscatter(const int* __restrict__ row,
                                                   const int* __restrict__ col,
                                                   const float* __restrict__ val,
                                                   const int* __restrict__ cnt,
                                                   uint2* __restrict__ tmp) {
    __shared__ int stage[SCHUNK];     // 64 KB: edge ids grouped by bucket
    __shared__ int hist[NB];
    __shared__ int lstart[NB];
    __shared__ int cur[NB];
    __shared__ int gbase[NB];
    __shared__ int scan[1024];

    const int g = blockIdx.x;
    const int t = threadIdx.x;
    const int lo = g * SCHUNK;
    const int hi = (lo + SCHUNK < NNZ_TOTAL) ? lo + SCHUNK : NNZ_TOTAL;
    const int n = hi - lo;

    // phase 1: histogram + fetch global bases
    if (t < NB) { hist[t] = 0; gbase[t] = cnt[t * SGRD + g]; }
    __syncthreads();
    for (int e = lo + t; e < hi; e += 1024)
        atomicAdd(&hist[row[e] >> 8], 1);
    __syncthreads();

    // phase 2: exclusive scan of 586 counters
    const int x = (t < NB) ? hist[t] : 0;
    scan[t] = x;
    __syncthreads();
    for (int off = 1; off < 1024; off <<= 1) {
        const int y = (t >= off) ? scan[t - off] : 0;
        __syncthreads();
        scan[t] += y;
        __syncthreads();
    }
    if (t < NB) {
        lstart[t] = scan[t] - x;
        cur[t] = scan[t] - x;
    }
    __syncthreads();

    // phase 3: place edge ids into bucket-grouped staging
    for (int e = lo + t; e < hi; e += 1024) {
        const int p = atomicAdd(&cur[row[e] >> 8], 1);
        stage[p] = e;
    }
    __syncthreads();

    // phase 4: ordered sweep -> contiguous writes per bucket run
    for (int l = t; l < n; l += 1024) {
        const int e = stage[l];
        const int r = row[e];
        const int b = r >> 8;
        const unsigned meta = ((unsigned)(r & (BROWS - 1)) << 18) | (unsigned)col[e];
        tmp[gbase[b] + (l - lstart[b])] = make_uint2(meta, __float_as_uint(val[e]));
    }
}

// per-bucket counting sort: bucket region ~137 KB -> L2-resident scatter
__global__ __launch_bounds__(256) void k_bsort(const uint2* __restrict__ tmp,
                                               uint2* __restrict__ csr,
                                               const int* __restrict__ bbase,
                                               int* __restrict__ row_offs) {
    __shared__ int cnt[BROWS];
    __shared__ int roff[BROWS];
    __shared__ int curl[BROWS];
    const int tid = threadIdx.x;
    const int b = blockIdx.x;
    const int s = bbase[b];
    const int e = bbase[b + 1];

    cnt[tid] = 0;
    __syncthreads();
    for (int j = s + tid; j < e; j += 256)
        atomicAdd(&cnt[tmp[j].x >> 18], 1);
    __syncthreads();
    if (tid == 0) {
        int a = 0;
        #pragma unroll
        for (int k = 0; k < BROWS; ++k) { roff[k] = a; a += cnt[k]; }
    }
    __syncthreads();
    {
        const int gr = b * BROWS + tid;
        if (gr < N_NODES) row_offs[gr] = s + roff[tid];
        curl[tid] = s + roff[tid];
    }
    __syncthreads();
    for (int j = s + tid; j < e; j += 256) {
        const uint2 u = tmp[j];
        const int p = atomicAdd(&curl[u.x >> 18], 1);
        csr[p] = u;
    }
    if (b == 0 && tid == 0) row_offs[N_NODES] = NNZ_TOTAL;
}

// ===========================================================================
// CSR SpMM, bf16 gather table: one wave per row; lane = sub*16 + d4.
// Accumulate f32; write next-layer bf16 table + f32 acc. Unroll-4 for MLP.
// ===========================================================================
template <bool FINAL>
__global__ __launch_bounds__(256) void k_spmm_bf16(const ushort4* __restrict__ T4,
                                                   ushort4* __restrict__ U4,
                                                   float4* __restrict__ ACC4,
                                                   const int* __restrict__ offs,
                                                   const uint2* __restrict__ csr) {
    const int lane = threadIdx.x & 63;
    const int sub  = lane >> 4;
    const int d4   = lane & 15;
    const int r = blockIdx.x * 4 + (threadIdx.x >> 6);
    const int s = offs[r];
    const int e = offs[r + 1];
    float4 acc = make_float4(0.f, 0.f, 0.f, 0.f);
    int j = s + sub;
    for (; j + 12 < e; j += 16) {
        const uint2 e0 = csr[j];
        const uint2 e1 = csr[j + 4];
        const uint2 e2 = csr[j + 8];
        const uint2 e3 = csr[j + 12];
        const ushort4 g0 = T4[(size_t)(e0.x & COLMASK) * 16 + d4];
        const ushort4 g1 = T4[(size_t)(e1.x & COLMASK) * 16 + d4];
        const ushort4 g2 = T4[(size_t)(e2.x & COLMASK) * 16 + d4];
        const ushort4 g3 = T4[(size_t)(e3.x & COLMASK) * 16 + d4];
        const float v0 = __uint_as_float(e0.y);
        const float v1 = __uint_as_float(e1.y);
        const float v2 = __uint_as_float(e2.y);
        const float v3 = __uint_as_float(e3.y);
        acc.x += v0 * bf2f(g0.x) + v1 * bf2f(g1.x) + v2 * bf2f(g2.x) + v3 * bf2f(g3.x);
        acc.y += v0 * bf2f(g0.y) + v1 * bf2f(g1.y) + v2 * bf2f(g2.y) + v3 * bf2f(g3.y);
        acc.z += v0 * bf2f(g0.z) + v1 * bf2f(g1.z) + v2 * bf2f(g2.z) + v3 * bf2f(g3.z);
        acc.w += v0 * bf2f(g0.w) + v1 * bf2f(g1.w) + v2 * bf2f(g2.w) + v3 * bf2f(g3.w);
    }
    for (; j + 4 < e; j += 8) {
        const uint2 e0 = csr[j];
        const uint2 e1 = csr[j + 4];
        const ushort4 g0 = T4[(size_t)(e0.x & COLMASK) * 16 + d4];
        const ushort4 g1 = T4[(size_t)(e1.x & COLMASK) * 16 + d4];
        const float v0 = __uint_as_float(e0.y);
        const float v1 = __uint_as_float(e1.y);
        acc.x += v0 * bf2f(g0.x) + v1 * bf2f(g1.x);
        acc.y += v0 * bf2f(g0.y) + v1 * bf2f(g1.y);
        acc.z += v0 * bf2f(g0.z) + v1 * bf2f(g1.z);
        acc.w += v0 * bf2f(g0.w) + v1 * bf2f(g1.w);
    }
    if (j < e) {
        const uint2 e0 = csr[j];
        const ushort4 g0 = T4[(size_t)(e0.x & COLMASK) * 16 + d4];
        const float v0 = __uint_as_float(e0.y);
        acc.x += v0 * bf2f(g0.x);
        acc.y += v0 * bf2f(g0.y);
        acc.z += v0 * bf2f(g0.z);
        acc.w += v0 * bf2f(g0.w);
    }
    #pragma unroll
    for (int m = 16; m <= 32; m <<= 1) {
        acc.x += __shfl_xor(acc.x, m, 64);
        acc.y += __shfl_xor(acc.y, m, 64);
        acc.z += __shfl_xor(acc.z, m, 64);
        acc.w += __shfl_xor(acc.w, m, 64);
    }
    if (sub == 0) {
        const size_t idx = (size_t)r * 16 + d4;
        float4 a = ACC4[idx];
        if (FINAL) {
            a.x = (a.x + acc.x) * 0.25f;
            a.y = (a.y + acc.y) * 0.25f;
            a.z = (a.z + acc.z) * 0.25f;
            a.w = (a.w + acc.w) * 0.25f;
            ACC4[idx] = a;
        } else {
            ushort4 t;
            t.x = f2bf(acc.x); t.y = f2bf(acc.y); t.z = f2bf(acc.z); t.w = f2bf(acc.w);
            U4[idx] = t;
            a.x += acc.x;
            a.y += acc.y;
            a.z += acc.z;
            a.w += acc.w;
            ACC4[idx] = a;
        }
    }
}

// ===========================================================================
// Last-resort fallback (round-1 atomic path; needs only 76.8 MB ws)
// ===========================================================================
__global__ __launch_bounds__(256) void k_init_f32(const float4* __restrict__ user,
                                                  const float4* __restrict__ item,
                                                  float4* __restrict__ A,
                                                  float4* __restrict__ acc) {
    const int stride = gridDim.x * blockDim.x;
    for (int i = blockIdx.x * blockDim.x + threadIdx.x; i < TOTAL4; i += stride) {
        float4 v = (i < USZ4) ? user[i] : item[i - USZ4];
        A[i] = v;
        acc[i] = v;
    }
}

__global__ __launch_bounds__(256) void k_spmm_atomic(const float* __restrict__ A,
                                                     float* __restrict__ B,
                                                     const float* __restrict__ val,
                                                     const int* __restrict__ row,
                                                     const int* __restrict__ col) {
    const int lane = threadIdx.x & 63;
    int wave = blockIdx.x * (blockDim.x >> 6) + (threadIdx.x >> 6);
    const int nw = gridDim.x * (blockDim.x >> 6);
    for (int e = wave; e < NNZ_TOTAL; e += nw) {
        const float x = A[col[e] * DIM + lane];
        unsafeAtomicAdd(&B[row[e] * DIM + lane], val[e] * x);
    }
}

__global__ __launch_bounds__(256) void k_accadd(float4* __restrict__ acc,
                                                const float4* __restrict__ B) {
    const int stride = gridDim.x * blockDim.x;
    for (int i = blockIdx.x * blockDim.x + threadIdx.x; i < TOTAL4; i += stride) {
        float4 a = acc[i];
        const float4 b = B[i];
        a.x += b.x; a.y += b.y; a.z += b.z; a.w += b.w;
        acc[i] = a;
    }
}

__global__ __launch_bounds__(256) void k_final(float4* __restrict__ acc,
                                               const float4* __restrict__ B) {
    const int stride = gridDim.x * blockDim.x;
    for (int i = blockIdx.x * blockDim.x + threadIdx.x; i < TOTAL4; i += stride) {
        float4 a = acc[i];
        const float4 b = B[i];
        a.x = (a.x + b.x) * 0.25f;
        a.y = (a.y + b.y) * 0.25f;
        a.z = (a.z + b.z) * 0.25f;
        a.w = (a.w + b.w) * 0.25f;
        acc[i] = a;
    }
}

extern "C" void kernel_launch(void* const* d_in, const int* in_sizes, int n_in,
                              void* d_out, int out_size, void* d_ws, size_t ws_size,
                              hipStream_t stream) {
    const float* user = (const float*)d_in[0];
    const float* item = (const float*)d_in[1];
    const float* val  = (const float*)d_in[2];
    const int*   row  = (const int*)d_in[3];
    const int*   col  = (const int*)d_in[4];

    float* acc = (float*)d_out;
    const int eltBlocks = 2048;

    // ws layout: [csr 80MB (overlay: cnt matrix during build)]
    //            [tmp 80MB (overlay: T0,T1 bf16 tables after bsort)]
    //            [misc: row_offs, bbase, rowsum]
    const size_t CSR_BYTES = (size_t)NNZ_TOTAL * 8;            // 80,000,000
    uint2* csr  = (uint2*)d_ws;
    int*   cnt  = (int*)d_ws;                                   // NB*SGRD ints, dead before bsort
    char*  reg1 = (char*)d_ws + CSR_BYTES;
    uint2* tmp  = (uint2*)reg1;
    ushort4* T0 = (ushort4*)reg1;                               // 19.2MB
    ushort4* T1 = T0 + TOTAL4;                                  // 19.2MB
    int* row_offs = (int*)(reg1 + CSR_BYTES);                   // N_NODES+1
    int* bbase    = row_offs + N_NODES + 1;                     // NB+1
    int* rowsum   = bbase + NB + 1;                             // NB

    const size_t needed =
        2 * CSR_BYTES + (size_t)(N_NODES + 1 + 2 * NB + 2) * 4;

    if (ws_size >= needed) {
        // ---- build bucketed CSR (no global atomics; LDS-staged scatter) ----
        k_lhist<<<SGRD, 256, 0, stream>>>(row, cnt);
        k_rowsum<<<NB, 256, 0, stream>>>(cnt, rowsum);
        k_sscan<<<1, 1024, 0, stream>>>(rowsum, bbase);
        k_rowscan<<<NB, 1024, 0, stream>>>(cnt, bbase);
        k_lscatter<<<SGRD, 1024, 0, stream>>>(row, col, val, cnt, tmp);
        k_bsort<<<NB, 256, 0, stream>>>(tmp, csr, bbase, row_offs);

        // ---- embeddings (T0/T1 overlay tmp; tmp dead after bsort) ----
        k_init<<<eltBlocks, 256, 0, stream>>>((const float4*)user, (const float4*)item,
                                              T0, (float4*)acc);

        const int rowBlocks = N_NODES / 4;   // 37500
        k_spmm_bf16<false><<<rowBlocks, 256, 0, stream>>>(
            T0, T1, (float4*)acc, row_offs, csr);
        k_spmm_bf16<false><<<rowBlocks, 256, 0, stream>>>(
            T1, T0, (float4*)acc, row_offs, csr);
        k_spmm_bf16<true><<<rowBlocks, 256, 0, stream>>>(
            T0, T1, (float4*)acc, row_offs, csr);
        return;
    }

    // ---- last resort: atomic path ----
    float* A2 = (float*)d_ws;
    float* B2 = A2 + TOTAL;
    k_init_f32<<<eltBlocks, 256, 0, stream>>>((const float4*)user, (const float4*)item,
                                              (float4*)A2, (float4*)acc);
    float* Af = A2;
    float* Bf = B2;
    for (int layer = 0; layer < 3; ++layer) {
        hipMemsetAsync(Bf, 0, (size_t)TOTAL * sizeof(float), stream);
        k_spmm_atomic<<<2048, 256, 0, stream>>>(Af, Bf, val, row, col);
        if (layer < 2) {
            k_accadd<<<eltBlocks, 256, 0, stream>>>((float4*)acc, (const float4*)Bf);
            float* t = Af; Af = Bf; Bf = t;
        } else {
            k_final<<<eltBlocks, 256, 0, stream>>>((float4*)acc, (const float4*)Bf);
        }
    }
}

// Round 8
// 735.655 us; speedup vs baseline: 1.2642x; 1.2642x over previous
//
#include <hip/hip_runtime.h>

#define N_USERS 100000
#define N_ITEMS 50000
#define N_NODES (N_USERS + N_ITEMS)   // 150000
#define DIM 64
#define NNZ_TOTAL 10000000
#define TOTAL (N_NODES * DIM)         // 9,600,000 floats
#define TOTAL4 (TOTAL / 4)            // 2,400,000 float4
#define USZ4 (N_USERS * DIM / 4)      // 1,600,000 float4

#define BROWS 256                     // rows per bucket
#define NB ((N_NODES + BROWS - 1) / BROWS)   // 586
#define SCHUNK 8192                   // edges per scatter chunk
#define SGRD ((NNZ_TOTAL + SCHUNK - 1) / SCHUNK)  // 1221
#define COLMASK 0x3FFFF               // 18 bits for col

__device__ __forceinline__ float bf2f(unsigned short u) {
    return __uint_as_float(((unsigned)u) << 16);
}
__device__ __forceinline__ unsigned short f2bf(float f) {
    unsigned b = __float_as_uint(f);
    b += 0x7FFFu + ((b >> 16) & 1u);   // RNE
    return (unsigned short)(b >> 16);
}

// ===========================================================================
// init: T0 = bf16(concat(user,item)); acc(d_out) = f32 concat
// ===========================================================================
__global__ __launch_bounds__(256) void k_init(const float4* __restrict__ user,
                                              const float4* __restrict__ item,
                                              ushort4* __restrict__ T0,
                                              float4* __restrict__ acc) {
    const int stride = gridDim.x * blockDim.x;
    for (int i = blockIdx.x * blockDim.x + threadIdx.x; i < TOTAL4; i += stride) {
        float4 v = (i < USZ4) ? user[i] : item[i - USZ4];
        acc[i] = v;
        ushort4 t;
        t.x = f2bf(v.x); t.y = f2bf(v.y); t.z = f2bf(v.z); t.w = f2bf(v.w);
        T0[i] = t;
    }
}

// ===========================================================================
// Bucketed CSR build. cnt matrix layout: cnt[b * SGRD + g]  (b-major)
// ===========================================================================
__global__ __launch_bounds__(256) void k_lhist(const int* __restrict__ row,
                                               int* __restrict__ cnt) {
    __shared__ int h[NB];
    for (int i = threadIdx.x; i < NB; i += 256) h[i] = 0;
    __syncthreads();
    const int g = blockIdx.x;
    const int lo = g * SCHUNK;
    const int hi = (lo + SCHUNK < NNZ_TOTAL) ? lo + SCHUNK : NNZ_TOTAL;
    for (int e = lo + threadIdx.x; e < hi; e += 256)
        atomicAdd(&h[row[e] >> 8], 1);
    __syncthreads();
    for (int b = threadIdx.x; b < NB; b += 256)
        cnt[b * SGRD + g] = h[b];
}

// scan phase 1: per-bucket row sums (586 blocks, coalesced)
__global__ __launch_bounds__(256) void k_rowsum(const int* __restrict__ cnt,
                                                int* __restrict__ rowsum) {
    __shared__ int lds[256];
    const int b = blockIdx.x;
    const int t = threadIdx.x;
    int s = 0;
    for (int k = t; k < SGRD; k += 256) s += cnt[b * SGRD + k];
    lds[t] = s;
    __syncthreads();
    #pragma unroll
    for (int off = 128; off > 0; off >>= 1) {
        if (t < off) lds[t] += lds[t + off];
        __syncthreads();
    }
    if (t == 0) rowsum[b] = lds[0];
}

// scan phase 2: exclusive scan of 586 row sums (single tiny block)
__global__ __launch_bounds__(1024) void k_sscan(const int* __restrict__ rowsum,
                                                int* __restrict__ bbase) {
    __shared__ int lds[1024];
    const int t = threadIdx.x;
    const int x = (t < NB) ? rowsum[t] : 0;
    lds[t] = x;
    __syncthreads();
    for (int off = 1; off < 1024; off <<= 1) {
        const int y = (t >= off) ? lds[t - off] : 0;
        __syncthreads();
        lds[t] += y;
        __syncthreads();
    }
    if (t < NB) bbase[t] = lds[t] - x;
    if (t == 1023) bbase[NB] = lds[1023];   // == NNZ
}

// scan phase 3: per-bucket exclusive scan over SGRD entries (2/thread) + base
__global__ __launch_bounds__(1024) void k_rowscan(int* __restrict__ cnt,
                                                  const int* __restrict__ bbase) {
    __shared__ int lds[1024];
    const int b = blockIdx.x;
    const int t = threadIdx.x;
    const int i0 = 2 * t, i1 = 2 * t + 1;
    const int a0 = (i0 < SGRD) ? cnt[b * SGRD + i0] : 0;
    const int a1 = (i1 < SGRD) ? cnt[b * SGRD + i1] : 0;
    const int s = a0 + a1;
    lds[t] = s;
    __syncthreads();
    for (int off = 1; off < 1024; off <<= 1) {
        const int y = (t >= off) ? lds[t - off] : 0;
        __syncthreads();
        lds[t] += y;
        __syncthreads();
    }
    const int pre = bbase[b] + lds[t] - s;
    if (i0 < SGRD) cnt[b * SGRD + i0] = pre;
    if (i1 < SGRD) cnt[b * SGRD + i1] = pre + a0;
}

// LDS-staged scatter, records staged in LDS (edges read ONCE, sequentially).
// Per-chunk bucket counts derived from the cnt matrix (no local histogram).
// Phase 4 recovers bucket via 10-step binary search over padded lstart.
__global__ __launch_bounds__(1024) void k_lscatter(const int* __restrict__ row,
                                                   const int* __restrict__ col,
                                                   const float* __restrict__ val,
                                                   const int* __restrict__ cnt,
                                                   const int* __restrict__ bbase,
                                                   uint2* __restrict__ tmp) {
    __shared__ uint2 stage[SCHUNK];   // 64 KB: full records grouped by bucket
    __shared__ int lstartp[1024];     // local bucket starts, padded w/ sentinel
    __shared__ int gbase[NB];
    __shared__ int cur[NB];
    __shared__ int scratch[1024];

    const int g = blockIdx.x;
    const int t = threadIdx.x;
    const int lo = g * SCHUNK;
    const int hi = (lo + SCHUNK < NNZ_TOTAL) ? lo + SCHUNK : NNZ_TOTAL;
    const int n = hi - lo;

    // phase 1: per-bucket global base + local count from cnt matrix
    int lcnt = 0;
    if (t < NB) {
        const int base = cnt[t * SGRD + g];
        gbase[t] = base;
        const int nxt = (g == SGRD - 1) ? bbase[t + 1] : cnt[t * SGRD + g + 1];
        lcnt = nxt - base;
    }
    scratch[t] = lcnt;
    __syncthreads();

    // phase 2: exclusive scan of local counts -> lstart
    for (int off = 1; off < 1024; off <<= 1) {
        const int y = (t >= off) ? scratch[t - off] : 0;
        __syncthreads();
        scratch[t] += y;
        __syncthreads();
    }
    const int ls = (t < NB) ? scratch[t] - lcnt : n;   // sentinel = n
    lstartp[t] = ls;
    if (t < NB) cur[t] = ls;
    __syncthreads();

    // phase 3: stream edges once (coalesced), stage records by bucket
    for (int e = lo + t; e < hi; e += 1024) {
        const int r = row[e];
        const unsigned meta = ((unsigned)(r & (BROWS - 1)) << 18) | (unsigned)col[e];
        const int p = atomicAdd(&cur[r >> 8], 1);
        stage[p] = make_uint2(meta, __float_as_uint(val[e]));
    }
    __syncthreads();

    // phase 4: ordered sweep -> contiguous global writes per bucket run
    for (int l = t; l < n; l += 1024) {
        int blo = 0, bhi = 1024;
        #pragma unroll
        for (int s = 0; s < 10; ++s) {
            const int mid = (blo + bhi) >> 1;
            if (lstartp[mid] <= l) blo = mid; else bhi = mid;
        }
        tmp[gbase[blo] + (l - lstartp[blo])] = stage[l];
    }
}

// per-bucket counting sort: bucket region ~137 KB -> L2-resident scatter
__global__ __launch_bounds__(256) void k_bsort(const uint2* __restrict__ tmp,
                                               uint2* __restrict__ csr,
                                               const int* __restrict__ bbase,
                                               int* __restrict__ row_offs) {
    __shared__ int cnt[BROWS];
    __shared__ int roff[BROWS];
    __shared__ int curl[BROWS];
    const int tid = threadIdx.x;
    const int b = blockIdx.x;
    const int s = bbase[b];
    const int e = bbase[b + 1];

    cnt[tid] = 0;
    __syncthreads();
    for (int j = s + tid; j < e; j += 256)
        atomicAdd(&cnt[tmp[j].x >> 18], 1);
    __syncthreads();
    if (tid == 0) {
        int a = 0;
        #pragma unroll
        for (int k = 0; k < BROWS; ++k) { roff[k] = a; a += cnt[k]; }
    }
    __syncthreads();
    {
        const int gr = b * BROWS + tid;
        if (gr < N_NODES) row_offs[gr] = s + roff[tid];
        curl[tid] = s + roff[tid];
    }
    __syncthreads();
    for (int j = s + tid; j < e; j += 256) {
        const uint2 u = tmp[j];
        const int p = atomicAdd(&curl[u.x >> 18], 1);
        csr[p] = u;
    }
    if (b == 0 && tid == 0) row_offs[N_NODES] = NNZ_TOTAL;
}

// ===========================================================================
// CSR SpMM, bf16 gather table: one wave per row; lane = sub*16 + d4.
// Accumulate f32; write next-layer bf16 table + f32 acc. Unroll-4 for MLP.
// ===========================================================================
template <bool FINAL>
__global__ __launch_bounds__(256) void k_spmm_bf16(const ushort4* __restrict__ T4,
                                                   ushort4* __restrict__ U4,
                                                   float4* __restrict__ ACC4,
                                                   const int* __restrict__ offs,
                                                   const uint2* __restrict__ csr) {
    const int lane = threadIdx.x & 63;
    const int sub  = lane >> 4;
    const int d4   = lane & 15;
    const int r = blockIdx.x * 4 + (threadIdx.x >> 6);
    const int s = offs[r];
    const int e = offs[r + 1];
    float4 acc = make_float4(0.f, 0.f, 0.f, 0.f);
    int j = s + sub;
    for (; j + 12 < e; j += 16) {
        const uint2 e0 = csr[j];
        const uint2 e1 = csr[j + 4];
        const uint2 e2 = csr[j + 8];
        const uint2 e3 = csr[j + 12];
        const ushort4 g0 = T4[(size_t)(e0.x & COLMASK) * 16 + d4];
        const ushort4 g1 = T4[(size_t)(e1.x & COLMASK) * 16 + d4];
        const ushort4 g2 = T4[(size_t)(e2.x & COLMASK) * 16 + d4];
        const ushort4 g3 = T4[(size_t)(e3.x & COLMASK) * 16 + d4];
        const float v0 = __uint_as_float(e0.y);
        const float v1 = __uint_as_float(e1.y);
        const float v2 = __uint_as_float(e2.y);
        const float v3 = __uint_as_float(e3.y);
        acc.x += v0 * bf2f(g0.x) + v1 * bf2f(g1.x) + v2 * bf2f(g2.x) + v3 * bf2f(g3.x);
        acc.y += v0 * bf2f(g0.y) + v1 * bf2f(g1.y) + v2 * bf2f(g2.y) + v3 * bf2f(g3.y);
        acc.z += v0 * bf2f(g0.z) + v1 * bf2f(g1.z) + v2 * bf2f(g2.z) + v3 * bf2f(g3.z);
        acc.w += v0 * bf2f(g0.w) + v1 * bf2f(g1.w) + v2 * bf2f(g2.w) + v3 * bf2f(g3.w);
    }
    for (; j + 4 < e; j += 8) {
        const uint2 e0 = csr[j];
        const uint2 e1 = csr[j + 4];
        const ushort4 g0 = T4[(size_t)(e0.x & COLMASK) * 16 + d4];
        const ushort4 g1 = T4[(size_t)(e1.x & COLMASK) * 16 + d4];
        const float v0 = __uint_as_float(e0.y);
        const float v1 = __uint_as_float(e1.y);
        acc.x += v0 * bf2f(g0.x) + v1 * bf2f(g1.x);
        acc.y += v0 * bf2f(g0.y) + v1 * bf2f(g1.y);
        acc.z += v0 * bf2f(g0.z) + v1 * bf2f(g1.z);
        acc.w += v0 * bf2f(g0.w) + v1 * bf2f(g1.w);
    }
    if (j < e) {
        const uint2 e0 = csr[j];
        const ushort4 g0 = T4[(size_t)(e0.x & COLMASK) * 16 + d4];
        const float v0 = __uint_as_float(e0.y);
        acc.x += v0 * bf2f(g0.x);
        acc.y += v0 * bf2f(g0.y);
        acc.z += v0 * bf2f(g0.z);
        acc.w += v0 * bf2f(g0.w);
    }
    #pragma unroll
    for (int m = 16; m <= 32; m <<= 1) {
        acc.x += __shfl_xor(acc.x, m, 64);
        acc.y += __shfl_xor(acc.y, m, 64);
        acc.z += __shfl_xor(acc.z, m, 64);
        acc.w += __shfl_xor(acc.w, m, 64);
    }
    if (sub == 0) {
        const size_t idx = (size_t)r * 16 + d4;
        float4 a = ACC4[idx];
        if (FINAL) {
            a.x = (a.x + acc.x) * 0.25f;
            a.y = (a.y + acc.y) * 0.25f;
            a.z = (a.z + acc.z) * 0.25f;
            a.w = (a.w + acc.w) * 0.25f;
            ACC4[idx] = a;
        } else {
            ushort4 t;
            t.x = f2bf(acc.x); t.y = f2bf(acc.y); t.z = f2bf(acc.z); t.w = f2bf(acc.w);
            U4[idx] = t;
            a.x += acc.x;
            a.y += acc.y;
            a.z += acc.z;
            a.w += acc.w;
            ACC4[idx] = a;
        }
    }
}

// ===========================================================================
// Last-resort fallback (round-1 atomic path; needs only 76.8 MB ws)
// ===========================================================================
__global__ __launch_bounds__(256) void k_init_f32(const float4* __restrict__ user,
                                                  const float4* __restrict__ item,
                                                  float4* __restrict__ A,
                                                  float4* __restrict__ acc) {
    const int stride = gridDim.x * blockDim.x;
    for (int i = blockIdx.x * blockDim.x + threadIdx.x; i < TOTAL4; i += stride) {
        float4 v = (i < USZ4) ? user[i] : item[i - USZ4];
        A[i] = v;
        acc[i] = v;
    }
}

__global__ __launch_bounds__(256) void k_spmm_atomic(const float* __restrict__ A,
                                                     float* __restrict__ B,
                                                     const float* __restrict__ val,
                                                     const int* __restrict__ row,
                                                     const int* __restrict__ col) {
    const int lane = threadIdx.x & 63;
    int wave = blockIdx.x * (blockDim.x >> 6) + (threadIdx.x >> 6);
    const int nw = gridDim.x * (blockDim.x >> 6);
    for (int e = wave; e < NNZ_TOTAL; e += nw) {
        const float x = A[col[e] * DIM + lane];
        unsafeAtomicAdd(&B[row[e] * DIM + lane], val[e] * x);
    }
}

__global__ __launch_bounds__(256) void k_accadd(float4* __restrict__ acc,
                                                const float4* __restrict__ B) {
    const int stride = gridDim.x * blockDim.x;
    for (int i = blockIdx.x * blockDim.x + threadIdx.x; i < TOTAL4; i += stride) {
        float4 a = acc[i];
        const float4 b = B[i];
        a.x += b.x; a.y += b.y; a.z += b.z; a.w += b.w;
        acc[i] = a;
    }
}

__global__ __launch_bounds__(256) void k_final(float4* __restrict__ acc,
                                               const float4* __restrict__ B) {
    const int stride = gridDim.x * blockDim.x;
    for (int i = blockIdx.x * blockDim.x + threadIdx.x; i < TOTAL4; i += stride) {
        float4 a = acc[i];
        const float4 b = B[i];
        a.x = (a.x + b.x) * 0.25f;
        a.y = (a.y + b.y) * 0.25f;
        a.z = (a.z + b.z) * 0.25f;
        a.w = (a.w + b.w) * 0.25f;
        acc[i] = a;
    }
}

extern "C" void kernel_launch(void* const* d_in, const int* in_sizes, int n_in,
                              void* d_out, int out_size, void* d_ws, size_t ws_size,
                              hipStream_t stream) {
    const float* user = (const float*)d_in[0];
    const float* item = (const float*)d_in[1];
    const float* val  = (const float*)d_in[2];
    const int*   row  = (const int*)d_in[3];
    const int*   col  = (const int*)d_in[4];

    float* acc = (float*)d_out;
    const int eltBlocks = 2048;

    // ws layout: [csr 80MB (overlay: cnt matrix during build)]
    //            [tmp 80MB (overlay: T0,T1 bf16 tables after bsort)]
    //            [misc: row_offs, bbase, rowsum]
    const size_t CSR_BYTES = (size_t)NNZ_TOTAL * 8;            // 80,000,000
    uint2* csr  = (uint2*)d_ws;
    int*   cnt  = (int*)d_ws;                                   // NB*SGRD ints (~2.9MB), dead before bsort
    char*  reg1 = (char*)d_ws + CSR_BYTES;
    uint2* tmp  = (uint2*)reg1;
    ushort4* T0 = (ushort4*)reg1;                               // 19.2MB
    ushort4* T1 = T0 + TOTAL4;                                  // 19.2MB
    int* row_offs = (int*)(reg1 + CSR_BYTES);                   // N_NODES+1
    int* bbase    = row_offs + N_NODES + 1;                     // NB+1
    int* rowsum   = bbase + NB + 1;                             // NB

    const size_t needed =
        2 * CSR_BYTES + (size_t)(N_NODES + 1 + 2 * NB + 2) * 4;

    if (ws_size >= needed) {
        // ---- build bucketed CSR (no global atomics; LDS record staging) ----
        k_lhist<<<SGRD, 256, 0, stream>>>(row, cnt);
        k_rowsum<<<NB, 256, 0, stream>>>(cnt, rowsum);
        k_sscan<<<1, 1024, 0, stream>>>(rowsum, bbase);
        k_rowscan<<<NB, 1024, 0, stream>>>(cnt, bbase);
        k_lscatter<<<SGRD, 1024, 0, stream>>>(row, col, val, cnt, bbase, tmp);
        k_bsort<<<NB, 256, 0, stream>>>(tmp, csr, bbase, row_offs);

        // ---- embeddings (T0/T1 overlay tmp; tmp dead after bsort) ----
        k_init<<<eltBlocks, 256, 0, stream>>>((const float4*)user, (const float4*)item,
                                              T0, (float4*)acc);

        const int rowBlocks = N_NODES / 4;   // 37500
        k_spmm_bf16<false><<<rowBlocks, 256, 0, stream>>>(
            T0, T1, (float4*)acc, row_offs, csr);
        k_spmm_bf16<false><<<rowBlocks, 256, 0, stream>>>(
            T1, T0, (float4*)acc, row_offs, csr);
        k_spmm_bf16<true><<<rowBlocks, 256, 0, stream>>>(
            T0, T1, (float4*)acc, row_offs, csr);
        return;
    }

    // ---- last resort: atomic path ----
    float* A2 = (float*)d_ws;
    float* B2 = A2 + TOTAL;
    k_init_f32<<<eltBlocks, 256, 0, stream>>>((const float4*)user, (const float4*)item,
                                              (float4*)A2, (float4*)acc);
    float* Af = A2;
    float* Bf = B2;
    for (int layer = 0; layer < 3; ++layer) {
        hipMemsetAsync(Bf, 0, (size_t)TOTAL * sizeof(float), stream);
        k_spmm_atomic<<<2048, 256, 0, stream>>>(Af, Bf, val, row, col);
        if (layer < 2) {
            k_accadd<<<eltBlocks, 256, 0, stream>>>((float4*)acc, (const float4*)Bf);
            float* t = Af; Af = Bf; Bf = t;
        } else {
            k_final<<<eltBlocks, 256, 0, stream>>>((float4*)acc, (const float4*)Bf);
        }
    }
}